// Round 16
// baseline (1110.450 us; speedup 1.0000x reference)
//
#include <hip/hip_runtime.h>
#include <hip/hip_bf16.h>
#include <stdint.h>

// Problem constants
#define BATCH   512
#define DIMS    512
#define NCLS    50000
#define KSUB    3
#define NW      150000   // NCLS*KSUB rows of weights
#define SCALE_F 64.0f
#define EPS_F   1e-12f

typedef __bf16 bf16x8 __attribute__((ext_vector_type(8)));
typedef __bf16 bf16x4 __attribute__((ext_vector_type(4)));
typedef float  f32x4  __attribute__((ext_vector_type(4)));

// async global->LDS, 16B per lane. LDS dest is wave-uniform base + lane*16.
__device__ __forceinline__ void gld16(const void* g, void* l) {
  __builtin_amdgcn_global_load_lds((const __attribute__((address_space(1))) void*)g,
                                   (__attribute__((address_space(3))) void*)l, 16, 0, 0);
}

// ---------------------------------------------------------------------------
// Prepass (x only): L2-normalize input rows in fp32, cast to bf16.
// ---------------------------------------------------------------------------
__global__ __launch_bounds__(256) void normalize_x(
    const float* __restrict__ x, __bf16* __restrict__ xb) {
  int wave = threadIdx.x >> 6, lane = threadIdx.x & 63;
  int r = blockIdx.x * 4 + wave;
  if (r >= BATCH) return;
  const float* src = x + (size_t)r * DIMS;
  __bf16* dst = xb + (size_t)r * DIMS;

  const float4* rp = (const float4*)src;
  float4 v0 = rp[lane];
  float4 v1 = rp[lane + 64];
  float s = v0.x*v0.x + v0.y*v0.y + v0.z*v0.z + v0.w*v0.w
          + v1.x*v1.x + v1.y*v1.y + v1.z*v1.z + v1.w*v1.w;
  #pragma unroll
  for (int m = 1; m < 64; m <<= 1) s += __shfl_xor(s, m, 64);
  float inv = 1.0f / fmaxf(sqrtf(s), EPS_F);

  bf16x4 o0, o1;
  o0[0] = (__bf16)(v0.x * inv); o0[1] = (__bf16)(v0.y * inv);
  o0[2] = (__bf16)(v0.z * inv); o0[3] = (__bf16)(v0.w * inv);
  o1[0] = (__bf16)(v1.x * inv); o1[1] = (__bf16)(v1.y * inv);
  o1[2] = (__bf16)(v1.z * inv); o1[3] = (__bf16)(v1.w * inv);
  bf16x4* wp = (bf16x4*)dst;
  wp[lane]      = o0;
  wp[lane + 64] = o1;
}

// ---------------------------------------------------------------------------
// Fused GEMM: out[b][c] = 64 * max_{k<3} ( (x_hat[b] . w[3c+k]) / ||w[3c+k]|| )
// Raw f32 weights; bf16 cast + Σw² during staging; norm applied in epilogue.
//
// History:
//  R3  (567us): XOR swizzle + 2-buffer 1-barrier/step.           [verified]
//  R7  (580us): counted-vmcnt ring = NULL (m114 implicit overlap).
//  R9  (569us): BK=64 = NULL -> not barrier-bound.
//  R10 (552us): XCD remap = -17us.                                [kept]
//  R14 (541us): fused w-norm; PMC: gemm=220us, MfmaUtil 14%, VALU 23%,
//    HBM 15%, Occ 20.6% -> LATENCY-BOUND, LDS 80KB caps 2 blocks/CU.
//  R15 change: BK 64->32. LDS 2x20KB=40KB -> 4 blocks/CU; bv[12]->bv[6]
//    (VGPR ~124->~100, launch_bounds(256,4)). Doubles TLP for the same
//    serial chain. Swizzle = R3's 64B-row involution slot^((row>>1)&3)
//    on all three paths (aload src, bstore, frag read).
// NOTE: epilogue i-loop MUST be fully unrolled — runtime indexing of acc[]
// demotes it to scratch (R1: VGPR=44, 8.5 GB HBM traffic, MfmaUtil 1.8%).
// ---------------------------------------------------------------------------
#define BM 128
#define BN 192
#define BK 32
#define BUFB 20480   // bytes per LDS buffer: (128+192)*32*2
#define NCT  782     // ceil(NW/BN) class-tiles

__global__ __launch_bounds__(256, 4) void gemm_max3(
    const __bf16* __restrict__ xb, const float* __restrict__ wf,
    float* __restrict__ out) {
  __shared__ __align__(16) char smem[2 * BUFB];   // 40 KB -> 4 blocks/CU

  const int bx   = blockIdx.x;
  const int xcd  = bx & 7;        // dispatch round-robins XCDs
  const int ci   = bx >> 3;
  const int mt   = ci & 3;        // 4 m-tiles of one class-tile: same XCD
  const int ct   = (ci >> 2) * 8 + xcd;
  if (ct >= NCT) return;          // uniform whole-block exit, before any barrier

  const int tid  = threadIdx.x;
  const int wave = tid >> 6;
  const int lane = tid & 63;
  const int m0   = mt * BM;
  const int n0   = ct * BN;       // w-row base (cos column base)

  const int wm   = wave & 1;      // row half (64 rows)
  const int wn   = wave >> 1;     // col half (96 cos cols)
  const int l15  = lane & 15;
  const int quad = lane >> 4;

  // A staging decode (gld16): 4 lanes per 64B row; physical slot lane&3
  // holds global slot (lane&3)^((srow>>1)&3), srow = lane>>2 (involution).
  const int srow = lane >> 2;
  const int scol = ((lane ^ (srow >> 1)) & 3) << 3;

  f32x4 acc[4][6] = {};
  float  bsq[6] = {};   // per-thread partial sum-of-squares (6 rows each)
  float4 bv[6];         // in-flight B f32 (T14 issue-early buffer)

  // B decode: row = s6*32 + (tid>>3) (0..191), c4 = lane&7 (float4 col 0..7).
  auto bload = [&](int kk) {
    #pragma unroll
    for (int s6 = 0; s6 < 6; ++s6) {
      int row  = s6 * 32 + (tid >> 3);
      int c4   = lane & 7;
      int grow = n0 + row; if (grow > NW - 1) grow = NW - 1;  // tail clamp
      bv[s6] = *((const float4*)(wf + (size_t)grow * DIMS + kk) + c4);
    }
  };
  auto bstore = [&](char* buf) {
    unsigned short* Bs = (unsigned short*)(buf + 8192);   // [192][32] bf16
    #pragma unroll
    for (int s6 = 0; s6 < 6; ++s6) {
      int row = s6 * 32 + (tid >> 3);
      int c4  = lane & 7;
      float4 v = bv[s6];
      bsq[s6] += v.x*v.x + v.y*v.y + v.z*v.z + v.w*v.w;
      bf16x4 o;
      o[0] = (__bf16)v.x; o[1] = (__bf16)v.y; o[2] = (__bf16)v.z; o[3] = (__bf16)v.w;
      int slot = (c4 >> 1) ^ ((row >> 1) & 3);   // same involution as read side
      *(bf16x4*)(Bs + row * 32 + slot * 8 + (c4 & 1) * 4) = o;
    }
  };
  auto aload = [&](int kk, char* buf) {
    unsigned short* As = (unsigned short*)buf;            // [128][32] bf16
    #pragma unroll
    for (int s2 = 0; s2 < 2; ++s2) {
      int s = wave * 2 + s2;   // 8 chunks of 16 rows, 2 per wave
      gld16(xb + (size_t)(m0 + s * 16 + srow) * DIMS + kk + scol, As + s * 512);
    }
  };

  auto compute = [&](const char* buf) {
    const unsigned short* As = (const unsigned short*)buf;
    const unsigned short* Bs = (const unsigned short*)(buf + 8192);
    bf16x8 a[4], bfr[6];
    #pragma unroll
    for (int i = 0; i < 4; ++i) {
      int r = wm * 64 + i * 16 + l15;
      int slot = quad ^ ((r >> 1) & 3);
      a[i] = *(const bf16x8*)(As + r * 32 + slot * 8);
    }
    #pragma unroll
    for (int j = 0; j < 6; ++j) {
      int r = wn * 96 + j * 16 + l15;
      int slot = quad ^ ((r >> 1) & 3);
      bfr[j] = *(const bf16x8*)(Bs + r * 32 + slot * 8);
    }
    #pragma unroll
    for (int i = 0; i < 4; ++i)
      #pragma unroll
      for (int j = 0; j < 6; ++j)
        acc[i][j] = __builtin_amdgcn_mfma_f32_16x16x32_bf16(a[i], bfr[j], acc[i][j], 0, 0, 0);
  };

  // prologue: fill buffer 0
  bload(0); aload(0, smem); bstore(smem);
  __syncthreads();

  int p = 0;
  #pragma unroll 1
  for (int kk = BK; kk < DIMS; kk += BK) {
    bload(kk);                          // issue f32 loads early (T14)
    aload(kk, smem + (p ^ 1) * BUFB);   // async A -> next buffer
    compute(smem + p * BUFB);           // MFMA hides B-load latency
    bstore(smem + (p ^ 1) * BUFB);      // cvt + swizzled ds_write
    __syncthreads();                    // drain vmcnt/lgkm + barrier
    p ^= 1;
  }
  compute(smem + p * BUFB);             // last tile
  __syncthreads();                      // all LDS reads done

  // ---- per-row inv-norms: reduce bsq across the 8 lanes sharing a row ----
  float* sqlds = (float*)(smem + 26624);   // 192 floats; beyond epilogue scratch
  #pragma unroll
  for (int k = 0; k < 6; ++k) {
    float v = bsq[k];
    v += __shfl_xor(v, 1, 64); v += __shfl_xor(v, 2, 64); v += __shfl_xor(v, 4, 64);
    if ((lane & 7) == 0) sqlds[k * 32 + (tid >> 3)] = v;
  }
  __syncthreads();
  float invw6[6];   // this thread's 6 column norms (cols wn*96 + j*16 + l15)
  #pragma unroll
  for (int j = 0; j < 6; ++j)
    invw6[j] = 1.0f / fmaxf(sqrtf(sqlds[wn * 96 + j * 16 + l15]), EPS_F);

  // ---- epilogue: per-wave LDS transpose, max over groups of 3 cols ----
  // scr: 16 rows x 100 floats (pitch 100 -> 2-way bank conflicts = free)
  float* scr = (float*)smem + wave * 1600;
  const int rl   = lane >> 2;   // read row 0..15
  const int gblk = lane & 3;    // 8-group block
  #pragma unroll
  for (int i = 0; i < 4; ++i) {   // FULL unroll: acc[] must stay in registers
    #pragma unroll
    for (int j = 0; j < 6; ++j)
      #pragma unroll
      for (int r = 0; r < 4; ++r)
        scr[(quad * 4 + r) * 100 + j * 16 + l15] = acc[i][j][r] * SCALE_F * invw6[j];
    __asm__ volatile("s_waitcnt lgkmcnt(0)" ::: "memory");

    float f[24];
    const float4* srcp = (const float4*)(scr + rl * 100 + gblk * 24);
    #pragma unroll
    for (int t = 0; t < 6; ++t) *(float4*)(f + 4 * t) = srcp[t];

    float o[8];
    #pragma unroll
    for (int t = 0; t < 8; ++t)
      o[t] = fmaxf(f[3 * t], fmaxf(f[3 * t + 1], f[3 * t + 2]));

    int brow = m0 + wm * 64 + i * 16 + rl;
    int cls0 = ct * 64 + wn * 32 + gblk * 8;
    float* op = out + (size_t)brow * NCLS + cls0;
    if (cls0 + 8 <= NCLS) {
      float4 s0 = {o[0], o[1], o[2], o[3]};
      float4 s1 = {o[4], o[5], o[6], o[7]};
      *(float4*)op = s0;
      *(float4*)(op + 4) = s1;
    } else {
      #pragma unroll
      for (int t = 0; t < 8; ++t)
        if (cls0 + t < NCLS) op[t] = o[t];
    }
    __asm__ volatile("s_waitcnt lgkmcnt(0)" ::: "memory");
  }
}

// ---------------------------------------------------------------------------
// Fixup: exact fp32 recompute of the 3 sub-center cosines at the label column.
// ---------------------------------------------------------------------------
__device__ __forceinline__ float d4(float4 a, float4 b) {
  return a.x * b.x + a.y * b.y + a.z * b.z + a.w * b.w;
}

__global__ __launch_bounds__(64) void fix_labels(
    const float* __restrict__ x, const int* __restrict__ label,
    const float* __restrict__ w, const float* __restrict__ margins,
    float* __restrict__ out) {
  int b = blockIdx.x;
  int lane = threadIdx.x;
  int c = label[b];
  const float4* xr = (const float4*)(x + (size_t)b * DIMS);
  const float4* w0 = (const float4*)(w + (size_t)(3 * c + 0) * DIMS);
  const float4* w1 = (const float4*)(w + (size_t)(3 * c + 1) * DIMS);
  const float4* w2 = (const float4*)(w + (size_t)(3 * c + 2) * DIMS);

  float xx = 0, n0 = 0, n1 = 0, n2 = 0, p0 = 0, p1 = 0, p2 = 0;
  #pragma unroll
  for (int t = 0; t < 2; ++t) {
    int i = lane + t * 64;
    float4 xv = xr[i], a0 = w0[i], a1 = w1[i], a2 = w2[i];
    xx += d4(xv, xv);
    n0 += d4(a0, a0); n1 += d4(a1, a1); n2 += d4(a2, a2);
    p0 += d4(xv, a0); p1 += d4(xv, a1); p2 += d4(xv, a2);
  }
  #pragma unroll
  for (int m = 1; m < 64; m <<= 1) {
    xx += __shfl_xor(xx, m, 64);
    n0 += __shfl_xor(n0, m, 64); n1 += __shfl_xor(n1, m, 64); n2 += __shfl_xor(n2, m, 64);
    p0 += __shfl_xor(p0, m, 64); p1 += __shfl_xor(p1, m, 64); p2 += __shfl_xor(p2, m, 64);
  }
  if (lane == 0) {
    float rx = 1.0f / fmaxf(sqrtf(xx), EPS_F);
    float r0 = 1.0f / fmaxf(sqrtf(n0), EPS_F);
    float r1 = 1.0f / fmaxf(sqrtf(n1), EPS_F);
    float r2 = 1.0f / fmaxf(sqrtf(n2), EPS_F);
    float c0 = p0 * rx * r0, c1 = p1 * rx * r1, c2 = p2 * rx * r2;
    float tgt = fmaxf(c0, fmaxf(c1, c2));
    float shift = 0.5f * (fabsf(c0 - c1) + fabsf(c0 - c2));
    float wm = margins[c] * (1.0f + shift);
    out[(size_t)b * NCLS + c] = SCALE_F * (tgt - wm);
  }
}

// ---------------------------------------------------------------------------
extern "C" void kernel_launch(void* const* d_in, const int* in_sizes, int n_in,
                              void* d_out, int out_size, void* d_ws, size_t ws_size,
                              hipStream_t stream) {
  const float* input   = (const float*)d_in[0];
  const int*   label   = (const int*)d_in[1];
  const float* weights = (const float*)d_in[2];
  const float* margins = (const float*)d_in[3];
  float* out = (float*)d_out;

  __bf16* x_bf = (__bf16*)d_ws;   // 512*512 bf16 = 512 KB

  // 1) normalize+cast input rows only (512 rows, 4 per block)
  normalize_x<<<BATCH / 4, 256, 0, stream>>>(input, x_bf);
  // 2) fused GEMM (raw f32 weights, in-kernel norm) + max3.
  //    grid padded to 8x4x98=3136 for the XCD remap (ct>=782 exits).
  gemm_max3<<<3136, 256, 0, stream>>>(x_bf, weights, out);
  // 3) exact fp32 fixup of label columns
  fix_labels<<<BATCH, 64, 0, stream>>>(input, label, weights, margins, out);
}

// Round 17
// 539.663 us; speedup vs baseline: 2.0577x; 2.0577x over previous
//
#include <hip/hip_runtime.h>
#include <hip/hip_bf16.h>
#include <stdint.h>

// Problem constants
#define BATCH   512
#define DIMS    512
#define NCLS    50000
#define KSUB    3
#define NW      150000   // NCLS*KSUB rows of weights
#define SCALE_F 64.0f
#define EPS_F   1e-12f

typedef __bf16 bf16x8 __attribute__((ext_vector_type(8)));
typedef __bf16 bf16x4 __attribute__((ext_vector_type(4)));
typedef float  f32x4  __attribute__((ext_vector_type(4)));

// async global->LDS, 16B per lane. LDS dest is wave-uniform base + lane*16.
__device__ __forceinline__ void gld16(const void* g, void* l) {
  __builtin_amdgcn_global_load_lds((const __attribute__((address_space(1))) void*)g,
                                   (__attribute__((address_space(3))) void*)l, 16, 0, 0);
}

// ---------------------------------------------------------------------------
// Prepass (x only): L2-normalize input rows in fp32, cast to bf16.
// ---------------------------------------------------------------------------
__global__ __launch_bounds__(256) void normalize_x(
    const float* __restrict__ x, __bf16* __restrict__ xb) {
  int wave = threadIdx.x >> 6, lane = threadIdx.x & 63;
  int r = blockIdx.x * 4 + wave;
  if (r >= BATCH) return;
  const float* src = x + (size_t)r * DIMS;
  __bf16* dst = xb + (size_t)r * DIMS;

  const float4* rp = (const float4*)src;
  float4 v0 = rp[lane];
  float4 v1 = rp[lane + 64];
  float s = v0.x*v0.x + v0.y*v0.y + v0.z*v0.z + v0.w*v0.w
          + v1.x*v1.x + v1.y*v1.y + v1.z*v1.z + v1.w*v1.w;
  #pragma unroll
  for (int m = 1; m < 64; m <<= 1) s += __shfl_xor(s, m, 64);
  float inv = 1.0f / fmaxf(sqrtf(s), EPS_F);

  bf16x4 o0, o1;
  o0[0] = (__bf16)(v0.x * inv); o0[1] = (__bf16)(v0.y * inv);
  o0[2] = (__bf16)(v0.z * inv); o0[3] = (__bf16)(v0.w * inv);
  o1[0] = (__bf16)(v1.x * inv); o1[1] = (__bf16)(v1.y * inv);
  o1[2] = (__bf16)(v1.z * inv); o1[3] = (__bf16)(v1.w * inv);
  bf16x4* wp = (bf16x4*)dst;
  wp[lane]      = o0;
  wp[lane + 64] = o1;
}

// ---------------------------------------------------------------------------
// Fused GEMM: out[b][c] = 64 * max_{k<3} ( (x_hat[b] . w[3c+k]) / ||w[3c+k]|| )
// Raw f32 weights; bf16 cast + Σw² during staging; norm applied in epilogue.
//
// History:
//  R3  (567us): XOR swizzle + 2-buffer 1-barrier/step.           [verified]
//  R7  (580us): counted-vmcnt ring = NULL (m114 implicit overlap).
//  R9  (569us): BK=64 = NULL -> not barrier-bound.
//  R10 (552us): XCD remap = -17us.                                [kept]
//  R14 (541us): fused w-norm; gemm=220us, MfmaUtil 14%, Occ 20.6%
//    -> latency-bound, LDS 80KB capped 2 blocks/CU.
//  R16 (1110us): BK=32 + launch_bounds(256,4) -> VGPR cap 128 < ~155 live
//    set; acc[] SPILLED (VGPR=64, WRITE 1.55GB, MfmaUtil 4%). REVERTED BOUND.
//  R17 change: launch_bounds(256,3) -> VGPR cap 170 fits ~155, no spill;
//    3 blocks/CU (LDS would allow 4, VGPR is the cap). 12 waves/CU = 1.5x
//    R14's TLP with the same fused pipeline.
// NOTE: epilogue i-loop MUST be fully unrolled — runtime indexing of acc[]
// demotes it to scratch (R1/R16: scratch spill = 8.5GB/2.4GB HBM traffic).
// ---------------------------------------------------------------------------
#define BM 128
#define BN 192
#define BK 32
#define BUFB 20480   // bytes per LDS buffer: (128+192)*32*2
#define NCT  782     // ceil(NW/BN) class-tiles

__global__ __launch_bounds__(256, 3) void gemm_max3(
    const __bf16* __restrict__ xb, const float* __restrict__ wf,
    float* __restrict__ out) {
  __shared__ __align__(16) char smem[2 * BUFB];   // 40 KB

  const int bx   = blockIdx.x;
  const int xcd  = bx & 7;        // dispatch round-robins XCDs
  const int ci   = bx >> 3;
  const int mt   = ci & 3;        // 4 m-tiles of one class-tile: same XCD
  const int ct   = (ci >> 2) * 8 + xcd;
  if (ct >= NCT) return;          // uniform whole-block exit, before any barrier

  const int tid  = threadIdx.x;
  const int wave = tid >> 6;
  const int lane = tid & 63;
  const int m0   = mt * BM;
  const int n0   = ct * BN;       // w-row base (cos column base)

  const int wm   = wave & 1;      // row half (64 rows)
  const int wn   = wave >> 1;     // col half (96 cos cols)
  const int l15  = lane & 15;
  const int quad = lane >> 4;

  // A staging decode (gld16): 4 lanes per 64B row; physical slot lane&3
  // holds global slot (lane&3)^((srow>>1)&3), srow = lane>>2 (involution).
  const int srow = lane >> 2;
  const int scol = ((lane ^ (srow >> 1)) & 3) << 3;

  f32x4 acc[4][6] = {};
  float  bsq[6] = {};   // per-thread partial sum-of-squares (6 rows each)
  float4 bv[6];         // in-flight B f32 (T14 issue-early buffer)

  // B decode: row = s6*32 + (tid>>3) (0..191), c4 = lane&7 (float4 col 0..7).
  auto bload = [&](int kk) {
    #pragma unroll
    for (int s6 = 0; s6 < 6; ++s6) {
      int row  = s6 * 32 + (tid >> 3);
      int c4   = lane & 7;
      int grow = n0 + row; if (grow > NW - 1) grow = NW - 1;  // tail clamp
      bv[s6] = *((const float4*)(wf + (size_t)grow * DIMS + kk) + c4);
    }
  };
  auto bstore = [&](char* buf) {
    unsigned short* Bs = (unsigned short*)(buf + 8192);   // [192][32] bf16
    #pragma unroll
    for (int s6 = 0; s6 < 6; ++s6) {
      int row = s6 * 32 + (tid >> 3);
      int c4  = lane & 7;
      float4 v = bv[s6];
      bsq[s6] += v.x*v.x + v.y*v.y + v.z*v.z + v.w*v.w;
      bf16x4 o;
      o[0] = (__bf16)v.x; o[1] = (__bf16)v.y; o[2] = (__bf16)v.z; o[3] = (__bf16)v.w;
      int slot = (c4 >> 1) ^ ((row >> 1) & 3);   // same involution as read side
      *(bf16x4*)(Bs + row * 32 + slot * 8 + (c4 & 1) * 4) = o;
    }
  };
  auto aload = [&](int kk, char* buf) {
    unsigned short* As = (unsigned short*)buf;            // [128][32] bf16
    #pragma unroll
    for (int s2 = 0; s2 < 2; ++s2) {
      int s = wave * 2 + s2;   // 8 chunks of 16 rows, 2 per wave
      gld16(xb + (size_t)(m0 + s * 16 + srow) * DIMS + kk + scol, As + s * 512);
    }
  };

  auto compute = [&](const char* buf) {
    const unsigned short* As = (const unsigned short*)buf;
    const unsigned short* Bs = (const unsigned short*)(buf + 8192);
    bf16x8 a[4], bfr[6];
    #pragma unroll
    for (int i = 0; i < 4; ++i) {
      int r = wm * 64 + i * 16 + l15;
      int slot = quad ^ ((r >> 1) & 3);
      a[i] = *(const bf16x8*)(As + r * 32 + slot * 8);
    }
    #pragma unroll
    for (int j = 0; j < 6; ++j) {
      int r = wn * 96 + j * 16 + l15;
      int slot = quad ^ ((r >> 1) & 3);
      bfr[j] = *(const bf16x8*)(Bs + r * 32 + slot * 8);
    }
    #pragma unroll
    for (int i = 0; i < 4; ++i)
      #pragma unroll
      for (int j = 0; j < 6; ++j)
        acc[i][j] = __builtin_amdgcn_mfma_f32_16x16x32_bf16(a[i], bfr[j], acc[i][j], 0, 0, 0);
  };

  // prologue: fill buffer 0
  bload(0); aload(0, smem); bstore(smem);
  __syncthreads();

  int p = 0;
  #pragma unroll 1
  for (int kk = BK; kk < DIMS; kk += BK) {
    bload(kk);                          // issue f32 loads early (T14)
    aload(kk, smem + (p ^ 1) * BUFB);   // async A -> next buffer
    compute(smem + p * BUFB);           // MFMA hides B-load latency
    bstore(smem + (p ^ 1) * BUFB);      // cvt + swizzled ds_write
    __syncthreads();                    // drain vmcnt/lgkm + barrier
    p ^= 1;
  }
  compute(smem + p * BUFB);             // last tile
  __syncthreads();                      // all LDS reads done

  // ---- per-row inv-norms: reduce bsq across the 8 lanes sharing a row ----
  float* sqlds = (float*)(smem + 26624);   // 192 floats; beyond epilogue scratch
  #pragma unroll
  for (int k = 0; k < 6; ++k) {
    float v = bsq[k];
    v += __shfl_xor(v, 1, 64); v += __shfl_xor(v, 2, 64); v += __shfl_xor(v, 4, 64);
    if ((lane & 7) == 0) sqlds[k * 32 + (tid >> 3)] = v;
  }
  __syncthreads();
  float invw6[6];   // this thread's 6 column norms (cols wn*96 + j*16 + l15)
  #pragma unroll
  for (int j = 0; j < 6; ++j)
    invw6[j] = 1.0f / fmaxf(sqrtf(sqlds[wn * 96 + j * 16 + l15]), EPS_F);

  // ---- epilogue: per-wave LDS transpose, max over groups of 3 cols ----
  // scr: 16 rows x 100 floats (pitch 100 -> 2-way bank conflicts = free)
  float* scr = (float*)smem + wave * 1600;
  const int rl   = lane >> 2;   // read row 0..15
  const int gblk = lane & 3;    // 8-group block
  #pragma unroll
  for (int i = 0; i < 4; ++i) {   // FULL unroll: acc[] must stay in registers
    #pragma unroll
    for (int j = 0; j < 6; ++j)
      #pragma unroll
      for (int r = 0; r < 4; ++r)
        scr[(quad * 4 + r) * 100 + j * 16 + l15] = acc[i][j][r] * SCALE_F * invw6[j];
    __asm__ volatile("s_waitcnt lgkmcnt(0)" ::: "memory");

    float f[24];
    const float4* srcp = (const float4*)(scr + rl * 100 + gblk * 24);
    #pragma unroll
    for (int t = 0; t < 6; ++t) *(float4*)(f + 4 * t) = srcp[t];

    float o[8];
    #pragma unroll
    for (int t = 0; t < 8; ++t)
      o[t] = fmaxf(f[3 * t], fmaxf(f[3 * t + 1], f[3 * t + 2]));

    int brow = m0 + wm * 64 + i * 16 + rl;
    int cls0 = ct * 64 + wn * 32 + gblk * 8;
    float* op = out + (size_t)brow * NCLS + cls0;
    if (cls0 + 8 <= NCLS) {
      float4 s0 = {o[0], o[1], o[2], o[3]};
      float4 s1 = {o[4], o[5], o[6], o[7]};
      *(float4*)op = s0;
      *(float4*)(op + 4) = s1;
    } else {
      #pragma unroll
      for (int t = 0; t < 8; ++t)
        if (cls0 + t < NCLS) op[t] = o[t];
    }
    __asm__ volatile("s_waitcnt lgkmcnt(0)" ::: "memory");
  }
}

// ---------------------------------------------------------------------------
// Fixup: exact fp32 recompute of the 3 sub-center cosines at the label column.
// ---------------------------------------------------------------------------
__device__ __forceinline__ float d4(float4 a, float4 b) {
  return a.x * b.x + a.y * b.y + a.z * b.z + a.w * b.w;
}

__global__ __launch_bounds__(64) void fix_labels(
    const float* __restrict__ x, const int* __restrict__ label,
    const float* __restrict__ w, const float* __restrict__ margins,
    float* __restrict__ out) {
  int b = blockIdx.x;
  int lane = threadIdx.x;
  int c = label[b];
  const float4* xr = (const float4*)(x + (size_t)b * DIMS);
  const float4* w0 = (const float4*)(w + (size_t)(3 * c + 0) * DIMS);
  const float4* w1 = (const float4*)(w + (size_t)(3 * c + 1) * DIMS);
  const float4* w2 = (const float4*)(w + (size_t)(3 * c + 2) * DIMS);

  float xx = 0, n0 = 0, n1 = 0, n2 = 0, p0 = 0, p1 = 0, p2 = 0;
  #pragma unroll
  for (int t = 0; t < 2; ++t) {
    int i = lane + t * 64;
    float4 xv = xr[i], a0 = w0[i], a1 = w1[i], a2 = w2[i];
    xx += d4(xv, xv);
    n0 += d4(a0, a0); n1 += d4(a1, a1); n2 += d4(a2, a2);
    p0 += d4(xv, a0); p1 += d4(xv, a1); p2 += d4(xv, a2);
  }
  #pragma unroll
  for (int m = 1; m < 64; m <<= 1) {
    xx += __shfl_xor(xx, m, 64);
    n0 += __shfl_xor(n0, m, 64); n1 += __shfl_xor(n1, m, 64); n2 += __shfl_xor(n2, m, 64);
    p0 += __shfl_xor(p0, m, 64); p1 += __shfl_xor(p1, m, 64); p2 += __shfl_xor(p2, m, 64);
  }
  if (lane == 0) {
    float rx = 1.0f / fmaxf(sqrtf(xx), EPS_F);
    float r0 = 1.0f / fmaxf(sqrtf(n0), EPS_F);
    float r1 = 1.0f / fmaxf(sqrtf(n1), EPS_F);
    float r2 = 1.0f / fmaxf(sqrtf(n2), EPS_F);
    float c0 = p0 * rx * r0, c1 = p1 * rx * r1, c2 = p2 * rx * r2;
    float tgt = fmaxf(c0, fmaxf(c1, c2));
    float shift = 0.5f * (fabsf(c0 - c1) + fabsf(c0 - c2));
    float wm = margins[c] * (1.0f + shift);
    out[(size_t)b * NCLS + c] = SCALE_F * (tgt - wm);
  }
}

// ---------------------------------------------------------------------------
extern "C" void kernel_launch(void* const* d_in, const int* in_sizes, int n_in,
                              void* d_out, int out_size, void* d_ws, size_t ws_size,
                              hipStream_t stream) {
  const float* input   = (const float*)d_in[0];
  const int*   label   = (const int*)d_in[1];
  const float* weights = (const float*)d_in[2];
  const float* margins = (const float*)d_in[3];
  float* out = (float*)d_out;

  __bf16* x_bf = (__bf16*)d_ws;   // 512*512 bf16 = 512 KB

  // 1) normalize+cast input rows only (512 rows, 4 per block)
  normalize_x<<<BATCH / 4, 256, 0, stream>>>(input, x_bf);
  // 2) fused GEMM (raw f32 weights, in-kernel norm) + max3.
  //    grid padded to 8x4x98=3136 for the XCD remap (ct>=782 exits).
  gemm_max3<<<3136, 256, 0, stream>>>(x_bf, weights, out);
  // 3) exact fp32 fixup of label columns
  fix_labels<<<BATCH, 64, 0, stream>>>(input, label, weights, margins, out);
}